// Round 1
// 398.433 us; speedup vs baseline: 2.8445x; 2.8445x over previous
//
#include <hip/hip_runtime.h>
#include <stdint.h>

#define NROWS 32768
#define KP    4000
#define KPAD  4096
#define DIM   128
#define CL    1000

typedef unsigned short u16;
typedef unsigned long long u64;
typedef unsigned short u16x8 __attribute__((ext_vector_type(8)));
typedef __bf16 bf16x8 __attribute__((ext_vector_type(8)));
typedef float f32x16 __attribute__((ext_vector_type(16)));

// ---------- helpers ----------

// Map float to a 32-bit key with the same total order (handles negatives).
__device__ __forceinline__ unsigned int f2ord(float f) {
    unsigned int u = __float_as_uint(f);
    return (u & 0x80000000u) ? ~u : (u | 0x80000000u);
}

__device__ __forceinline__ u16 bf16rne(float f) {
    unsigned u = __float_as_uint(f);
    return (u16)((u + 0x7FFFu + ((u >> 16) & 1u)) >> 16);
}
__device__ __forceinline__ float bf2f(u16 h) {
    return __uint_as_float(((unsigned)h) << 16);
}
// 3-way bf16 split: v ~= h + m + l with |err| ~ 2^-27 |v|
__device__ __forceinline__ void split3(float v, u16& h, u16& m, u16& l) {
    h = bf16rne(v);
    float r1 = v - bf2f(h);
    m = bf16rne(r1);
    float r2 = r1 - bf2f(m);
    l = bf16rne(r2);
}

__device__ __forceinline__ f32x16 mfma16(bf16x8 a, bf16x8 b, f32x16 c) {
    return __builtin_amdgcn_mfma_f32_32x32x16_bf16(a, b, c, 0, 0, 0);
}

// ---------- prep: packed init, p2 (padded, +inf tail), bf16 splits ----------
// psplit layout (ushort): [s:3][k:4096][d:128]         (s-stride 524288)
// xfrag  layout (ushort): [g:1024][kk:8][s:3][lane:64][e:8]
//   element (g,kk,s,lane,e) = x_s[g*32 + (lane&31)][kk*16 + (lane>>5)*8 + e]
//   -> a wave's B-fragment load is one coalesced 1KB b128 per (kk,s).
__global__ void prep_kernel(const float* __restrict__ x,
                            const float* __restrict__ proxies,
                            u16* __restrict__ xfrag,
                            u16* __restrict__ psplit,
                            float* __restrict__ p2pad,
                            u64* __restrict__ packed) {
    int i = blockIdx.x * 256 + threadIdx.x;        // grid 1408*256 = 360448
    if (i < NROWS) packed[i] = ~0ull;
    if (i < KPAD) {
        if (i < KP) {
            // identical fp32 chain to the previously-passing kernel
            const float4* p = (const float4*)(proxies + (size_t)i * DIM);
            float s = 0.f;
            #pragma unroll
            for (int d = 0; d < DIM / 4; d++) {
                float4 v = p[d];
                s = fmaf(v.x, v.x, s);
                s = fmaf(v.y, v.y, s);
                s = fmaf(v.z, v.z, s);
                s = fmaf(v.w, v.w, s);
            }
            p2pad[i] = s;
        } else {
            p2pad[i] = __builtin_inff();           // padded proxies never win
        }
    }
    if (i >= 32768 && i < 98304) {                 // proxy splits: (k, 8-col chunk)
        int j = i - 32768;
        int k = j >> 4, c = j & 15;
        float vals[8];
        if (k < KP) {
            const float4* p = (const float4*)(proxies + (size_t)k * DIM + c * 8);
            float4 a = p[0], b = p[1];
            vals[0]=a.x; vals[1]=a.y; vals[2]=a.z; vals[3]=a.w;
            vals[4]=b.x; vals[5]=b.y; vals[6]=b.z; vals[7]=b.w;
        } else {
            #pragma unroll
            for (int e = 0; e < 8; e++) vals[e] = 0.f;
        }
        u16x8 vh, vm, vl;
        #pragma unroll
        for (int e = 0; e < 8; e++) {
            u16 h, m, l; split3(vals[e], h, m, l);
            vh[e] = h; vm[e] = m; vl[e] = l;
        }
        u16* dst = psplit + ((size_t)k << 7) + (c << 3);
        *(u16x8*)(dst)           = vh;
        *(u16x8*)(dst + 524288)  = vm;
        *(u16x8*)(dst + 1048576) = vl;
    }
    if (i >= 98304) {                              // x fragments: (n, kk)
        int j = i - 98304;                         // [0, 262144)
        int n = j & 32767, kk = j >> 15;
        const float4* xp = (const float4*)(x + (size_t)n * DIM + kk * 16);
        float4 a = xp[0], b = xp[1], cc = xp[2], d4 = xp[3];
        float vals[16] = {a.x,a.y,a.z,a.w, b.x,b.y,b.z,b.w,
                          cc.x,cc.y,cc.z,cc.w, d4.x,d4.y,d4.z,d4.w};
        u16x8 h0,h1,m0,m1,l0v,l1v;
        #pragma unroll
        for (int e = 0; e < 8; e++) {
            u16 h,m,l; split3(vals[e], h,m,l);
            h0[e]=h; m0[e]=m; l0v[e]=l;
        }
        #pragma unroll
        for (int e = 0; e < 8; e++) {
            u16 h,m,l; split3(vals[8+e], h,m,l);
            h1[e]=h; m1[e]=m; l1v[e]=l;
        }
        int g = n >> 5, ln = n & 31;
        u16* base = xfrag + (size_t)g*12288 + (size_t)kk*1536 + (size_t)ln*8;
        *(u16x8*)(base)        = h0;               // lane ln   (d = kk*16+0..7)
        *(u16x8*)(base + 512)  = m0;
        *(u16x8*)(base + 1024) = l0v;
        u16* base1 = base + 256;                   // lane ln+32 (d = kk*16+8..15)
        *(u16x8*)(base1)        = h1;
        *(u16x8*)(base1 + 512)  = m1;
        *(u16x8*)(base1 + 1024) = l1v;
    }
}

// ---------- argmin via bf16 6-term split GEMM on matrix cores ----------
// Block: 256 thr = 4 waves; wave w owns x-row-group g = blockIdx.x*4+w (32 rows).
// blockIdx.y in {0,1} selects 32 of the 64 proxy tiles (64 proxies each).
// A operand = proxies (LDS, XOR-swizzled: chunk ^= row&7 kills the 32-way
// bank conflict of the 256B row stride). B operand = x splits in 96 VGPRs.
// score = p2[k] - 2*dot (monotone in the true distance); per-lane running min,
// shfl_xor(32) pair-reduce, packed u64 atomicMin (first-min tie-break).
__global__ void __launch_bounds__(256, 2)
argmin_mfma(const u16* __restrict__ xfrag,
            const u16* __restrict__ psplit,
            const float* __restrict__ p2pad,
            u64* __restrict__ packed) {
    __shared__ __align__(16) u16 ldsP[24576];      // 3 splits x 64 rows x 128 (48KB)
    __shared__ __align__(16) float ldsP2[64];
    const int tid  = threadIdx.x;
    const int lane = tid & 63;
    const int w    = tid >> 6;
    const int g    = blockIdx.x * 4 + w;
    const int r31  = lane & 31;
    const int hl   = lane >> 5;
    const int r7   = r31 & 7;

    // B fragments: x splits for this wave's 32 rows, all of D, in registers.
    bf16x8 xf[3][8];
    {
        const u16* base = xfrag + (size_t)g * 12288 + lane * 8;
        #pragma unroll
        for (int kk = 0; kk < 8; kk++)
            #pragma unroll
            for (int s = 0; s < 3; s++)
                xf[s][kk] = *(const bf16x8*)(base + (kk*3 + s) * 512);
    }

    float best = __builtin_inff();
    int bestk = 0;
    const int tilebase = blockIdx.y * 32;

    for (int t = 0; t < 32; t++) {
        const int tile = tilebase + t;
        // stage 64-proxy tile (3 splits) into LDS, swizzled on write
        #pragma unroll
        for (int i = 0; i < 12; i++) {
            int F = tid * 8 + i * 2048;            // ushort offset in 24576
            int s = F >> 13;
            int rem = F & 8191;
            int row = rem >> 7;
            int chunk = (rem >> 3) & 15;
            u16x8 v = *(const u16x8*)(psplit + (size_t)s * 524288 +
                                      ((size_t)(tile * 64 + row) << 7) + (chunk << 3));
            *(u16x8*)(ldsP + (s << 13) + (row << 7) + ((chunk ^ (row & 7)) << 3)) = v;
        }
        if (tid < 64) ldsP2[tid] = p2pad[tile * 64 + tid];
        __syncthreads();

        // two independent acc chains (proxy sub-tiles 0..31 / 32..63) for MFMA ILP
        f32x16 acc0 = {0,0,0,0,0,0,0,0,0,0,0,0,0,0,0,0};
        f32x16 acc1 = {0,0,0,0,0,0,0,0,0,0,0,0,0,0,0,0};
        #pragma unroll
        for (int kk = 0; kk < 8; kk++) {
            int c = (kk * 2 + hl) ^ r7;            // swizzled 16B chunk index
            int off0 = (r31 << 7) + (c << 3);
            int off1 = off0 + (32 << 7);           // rows+32: (row&7) unchanged
            bf16x8 a0h = *(const bf16x8*)(ldsP + off0);
            bf16x8 a0m = *(const bf16x8*)(ldsP + 8192 + off0);
            bf16x8 a0l = *(const bf16x8*)(ldsP + 16384 + off0);
            bf16x8 a1h = *(const bf16x8*)(ldsP + off1);
            bf16x8 a1m = *(const bf16x8*)(ldsP + 8192 + off1);
            bf16x8 a1l = *(const bf16x8*)(ldsP + 16384 + off1);
            bf16x8 bh = xf[0][kk], bm = xf[1][kk], bl = xf[2][kk];
            // 6 terms down to 2^-18: hh, hm, mh, hl, lh, mm — all into same acc
            acc0 = mfma16(a0h, bh, acc0);  acc1 = mfma16(a1h, bh, acc1);
            acc0 = mfma16(a0h, bm, acc0);  acc1 = mfma16(a1h, bm, acc1);
            acc0 = mfma16(a0m, bh, acc0);  acc1 = mfma16(a1m, bh, acc1);
            acc0 = mfma16(a0h, bl, acc0);  acc1 = mfma16(a1h, bl, acc1);
            acc0 = mfma16(a0l, bh, acc0);  acc1 = mfma16(a1l, bh, acc1);
            acc0 = mfma16(a0m, bm, acc0);  acc1 = mfma16(a1m, bm, acc1);
        }

        // scores + running argmin. C layout: col=lane&31 (x-row),
        // proxy row = (reg&3) + 8*(reg>>2) + 4*hl, reg = 4j+e.
        int kb = tile * 64;
        #pragma unroll
        for (int j = 0; j < 4; j++) {
            float4 q = *(const float4*)(ldsP2 + hl * 4 + j * 8);
            float qa[4] = {q.x, q.y, q.z, q.w};
            #pragma unroll
            for (int e = 0; e < 4; e++) {
                float sc = fmaf(-2.f, acc0[j*4+e], qa[e]);
                int ki = kb + 4*hl + 8*j + e;
                if (sc < best) { best = sc; bestk = ki; }  // strict <: first-min
            }
        }
        #pragma unroll
        for (int j = 0; j < 4; j++) {
            float4 q = *(const float4*)(ldsP2 + 32 + hl * 4 + j * 8);
            float qa[4] = {q.x, q.y, q.z, q.w};
            #pragma unroll
            for (int e = 0; e < 4; e++) {
                float sc = fmaf(-2.f, acc1[j*4+e], qa[e]);
                int ki = kb + 32 + 4*hl + 8*j + e;
                if (sc < best) { best = sc; bestk = ki; }
            }
        }
        __syncthreads();                           // before next tile overwrites LDS
    }

    u64 key = ((u64)f2ord(best) << 32) | (unsigned)bestk;
    u64 other = __shfl_xor(key, 32);
    key = other < key ? other : key;
    if (hl == 0) atomicMin(&packed[(size_t)g * 32 + r31], key);
}

// ---------- epilogue copies ----------

// out[0 : N*D) = x ; out[N*D : 2*N*D) = proxies[idx]
__global__ void copy_x_proxy(const float4* __restrict__ x4,
                             const float4* __restrict__ prox4,
                             const u64* __restrict__ packed,
                             float4* __restrict__ out4) {
    int i = blockIdx.x * blockDim.x + threadIdx.x;   // 8192 x 256
    const int R0 = NROWS * (DIM / 4);
    if (i < R0) {
        out4[i] = x4[i];
    } else {
        int j = i - R0;
        int n = j >> 5;           // DIM/4 = 32
        int d = j & 31;
        int k = (int)(unsigned int)(packed[n] & 0xFFFFFFFFull);
        out4[i] = prox4[(long)k * (DIM / 4) + d];
    }
}

// out[2*N*D : ...) = labels[idx] ; 4 rows/block, 1 wave per row
__global__ void gather_labels(const float4* __restrict__ lab4,
                              const u64* __restrict__ packed,
                              float4* __restrict__ out4) {
    int rr = threadIdx.x >> 6;
    int ln = threadIdx.x & 63;
    int n = blockIdx.x * 4 + rr;                     // 8192 blocks
    int k = (int)(unsigned int)(packed[n] & 0xFFFFFFFFull);
    const float4* src = lab4 + (size_t)k * (CL / 4);
    float4* dst = out4 + (size_t)n * (CL / 4);
    for (int d = ln; d < CL / 4; d += 64) dst[d] = src[d];
}

extern "C" void kernel_launch(void* const* d_in, const int* in_sizes, int n_in,
                              void* d_out, int out_size, void* d_ws, size_t ws_size,
                              hipStream_t stream) {
    const float* x       = (const float*)d_in[0];
    const float* proxies = (const float*)d_in[1];
    const float* labels  = (const float*)d_in[2];
    float* out = (float*)d_out;

    // workspace map (needs ~28MB):
    //   [0, 256K)        packed u64[32768]
    //   [256K, 272K)     p2pad f32[4096]
    //   [512K, ~3.6M)    psplit u16 [3][4096][128]
    //   [4M, ~28M)       xfrag  u16 [1024][8][3][64][8]
    u64*   packed = (u64*)d_ws;
    float* p2pad  = (float*)((char*)d_ws + 262144);
    u16*   psplit = (u16*)((char*)d_ws + 524288);
    u16*   xfrag  = (u16*)((char*)d_ws + 4194304);

    prep_kernel<<<1408, 256, 0, stream>>>(x, proxies, xfrag, psplit, p2pad, packed);

    argmin_mfma<<<dim3(256, 2), 256, 0, stream>>>(xfrag, psplit, p2pad, packed);

    copy_x_proxy<<<8192, 256, 0, stream>>>(
        (const float4*)x, (const float4*)proxies, packed, (float4*)out);

    gather_labels<<<8192, 256, 0, stream>>>(
        (const float4*)labels, packed, (float4*)(out + 2L * NROWS * DIM));
}

// Round 4
// 360.990 us; speedup vs baseline: 3.1395x; 1.1037x over previous
//
#include <hip/hip_runtime.h>
#include <stdint.h>

#define NROWS 32768
#define KP    4000
#define KPAD  4096
#define DIM   128
#define CL    1000
#define NHALF 128          // KPAD / 32 proxies per half-tile
#define HREAL 125          // ceil(KP/32): halves containing real proxies

typedef unsigned short u16;
typedef unsigned long long u64;
typedef unsigned short u16x8 __attribute__((ext_vector_type(8)));
typedef __bf16 bf16x8 __attribute__((ext_vector_type(8)));
typedef float f32x16 __attribute__((ext_vector_type(16)));
typedef float f32x4 __attribute__((ext_vector_type(4)));   // for nontemporal stores

// ---------- helpers ----------

// Map float to a 32-bit key with the same total order (handles negatives).
__device__ __forceinline__ unsigned int f2ord(float f) {
    unsigned int u = __float_as_uint(f);
    return (u & 0x80000000u) ? ~u : (u | 0x80000000u);
}

__device__ __forceinline__ u16 bf16rne(float f) {
    unsigned u = __float_as_uint(f);
    return (u16)((u + 0x7FFFu + ((u >> 16) & 1u)) >> 16);
}
__device__ __forceinline__ float bf2f(u16 h) {
    return __uint_as_float(((unsigned)h) << 16);
}
// 3-way bf16 split: v ~= h + m + l with |err| ~ 2^-27 |v|
__device__ __forceinline__ void split3(float v, u16& h, u16& m, u16& l) {
    h = bf16rne(v);
    float r1 = v - bf2f(h);
    m = bf16rne(r1);
    float r2 = r1 - bf2f(m);
    l = bf16rne(r2);
}

__device__ __forceinline__ f32x16 mfma16(bf16x8 a, bf16x8 b, f32x16 c) {
    return __builtin_amdgcn_mfma_f32_32x32x16_bf16(a, b, c, 0, 0, 0);
}

// async global->LDS 16B per lane; dest must be linear (base + lane*16).
__device__ __forceinline__ void g2lds16(const void* g, void* l) {
    __builtin_amdgcn_global_load_lds(
        (const __attribute__((address_space(1))) unsigned int*)(uintptr_t)g,
        (__attribute__((address_space(3))) unsigned int*)(uintptr_t)l,
        16, 0, 0);
}

// nontemporal 16B store wrapper (clang builtin needs ext-vector, not float4)
__device__ __forceinline__ void nt_store4(const float4& v, float4* dst) {
    __builtin_nontemporal_store(*(const f32x4*)&v, (f32x4*)dst);
}

// ---------- prep ----------
// psplit_sw layout (ushort): [half:128][s:3][row:32][chunkpos:16][e:8]
//   chunkpos = chunk ^ (row & 7)  -- the LDS image is PRE-swizzled so the
//   argmin kernel can stage it with linear global_load_lds (rule #21).
// xfrag layout (ushort): [g:1024][kk:8][s:3][lane:64][e:8]
//   element (g,kk,s,lane,e) = x_s[g*32 + (lane&31)][kk*16 + (lane>>5)*8 + e]
// Also: packed init, p2pad (+inf tail), and out[0:N*D) = x (fused x-copy;
// tail thread j copies FOUR float4s at stride 262144 -> covers all 1048576).
__global__ void prep_kernel(const float* __restrict__ x,
                            const float* __restrict__ proxies,
                            u16* __restrict__ xfrag,
                            u16* __restrict__ psplit_sw,
                            float* __restrict__ p2pad,
                            u64* __restrict__ packed,
                            float4* __restrict__ outx4) {
    int i = blockIdx.x * 256 + threadIdx.x;        // grid 2432*256 = 622592
    if (i < NROWS) packed[i] = ~0ull;
    if (i < KPAD) {
        if (i < KP) {
            const float4* p = (const float4*)(proxies + (size_t)i * DIM);
            float s = 0.f;
            #pragma unroll
            for (int d = 0; d < DIM / 4; d++) {
                float4 v = p[d];
                s = fmaf(v.x, v.x, s);
                s = fmaf(v.y, v.y, s);
                s = fmaf(v.z, v.z, s);
                s = fmaf(v.w, v.w, s);
            }
            p2pad[i] = s;
        } else {
            p2pad[i] = __builtin_inff();           // padded proxies never win
        }
    }
    if (i >= 32768 && i < 98304) {                 // proxy splits: (k, 8-col chunk)
        int j = i - 32768;
        int k = j >> 4, c = j & 15;
        float vals[8];
        if (k < KP) {
            const float4* p = (const float4*)(proxies + (size_t)k * DIM + c * 8);
            float4 a = p[0], b = p[1];
            vals[0]=a.x; vals[1]=a.y; vals[2]=a.z; vals[3]=a.w;
            vals[4]=b.x; vals[5]=b.y; vals[6]=b.z; vals[7]=b.w;
        } else {
            #pragma unroll
            for (int e = 0; e < 8; e++) vals[e] = 0.f;
        }
        u16x8 vh, vm, vl;
        #pragma unroll
        for (int e = 0; e < 8; e++) {
            u16 h, m, l; split3(vals[e], h, m, l);
            vh[e] = h; vm[e] = m; vl[e] = l;
        }
        // pre-swizzled position within the half-tile image
        u16* dst = psplit_sw + (size_t)(k >> 5) * 12288 +
                   (size_t)(k & 31) * 128 + ((c ^ (k & 7)) << 3);
        *(u16x8*)(dst)        = vh;
        *(u16x8*)(dst + 4096) = vm;                // s stride = 32*128
        *(u16x8*)(dst + 8192) = vl;
    }
    if (i >= 98304 && i < 360448) {                // x fragments: (n, kk)
        int j = i - 98304;                         // [0, 262144)
        int n = j & 32767, kk = j >> 15;
        const float4* xp = (const float4*)(x + (size_t)n * DIM + kk * 16);
        float4 a = xp[0], b = xp[1], cc = xp[2], d4 = xp[3];
        float vals[16] = {a.x,a.y,a.z,a.w, b.x,b.y,b.z,b.w,
                          cc.x,cc.y,cc.z,cc.w, d4.x,d4.y,d4.z,d4.w};
        u16x8 h0,h1,m0,m1,l0v,l1v;
        #pragma unroll
        for (int e = 0; e < 8; e++) {
            u16 h,m,l; split3(vals[e], h,m,l);
            h0[e]=h; m0[e]=m; l0v[e]=l;
        }
        #pragma unroll
        for (int e = 0; e < 8; e++) {
            u16 h,m,l; split3(vals[8+e], h,m,l);
            h1[e]=h; m1[e]=m; l1v[e]=l;
        }
        int g = n >> 5, ln = n & 31;
        u16* base = xfrag + (size_t)g*12288 + (size_t)kk*1536 + (size_t)ln*8;
        *(u16x8*)(base)        = h0;               // lane ln   (d = kk*16+0..7)
        *(u16x8*)(base + 512)  = m0;
        *(u16x8*)(base + 1024) = l0v;
        u16* base1 = base + 256;                   // lane ln+32 (d = kk*16+8..15)
        *(u16x8*)(base1)        = h1;
        *(u16x8*)(base1 + 512)  = m1;
        *(u16x8*)(base1 + 1024) = l1v;
    }
    if (i >= 360448) {                             // out[0:N*D) = x (coalesced)
        int j = i - 360448;                        // [0, 262144)
        const float4* src = (const float4*)x;
        #pragma unroll
        for (int t = 0; t < 4; t++)                // 4 x 262144 = 1048576 float4
            nt_store4(src[j + t * 262144], outx4 + j + t * 262144);
    }
}

// ---------- argmin via bf16 6-term split GEMM on matrix cores ----------
// 256 thr = 4 waves; wave w owns x-row-group g = blockIdx.x*4+w (32 rows, B
// operand in 96 VGPRs). Proxies stream through a double-buffered 2x24KB LDS
// half-tile (32 proxies x 3 splits), staged with linear global_load_lds from
// the pre-swizzled psplit_sw image; stage of half h+1 is issued BEFORE the
// MFMAs of half h (latency hidden), single vmcnt(0)+barrier per half.
// score = p2[k] - 2*dot; per-lane running min, shfl_xor(32) pair-reduce,
// packed u64 atomicMin (first-min tie-break preserved).
__global__ void __launch_bounds__(256, 3)
argmin_mfma(const u16* __restrict__ xfrag,
            const u16* __restrict__ psplit_sw,
            const float* __restrict__ p2pad,
            u64* __restrict__ packed) {
    __shared__ __align__(16) u16 buf[2][12288];    // 2 x 24KB
    const int tid  = threadIdx.x;
    const int lane = tid & 63;
    const int w    = tid >> 6;
    const int g    = blockIdx.x * 4 + w;
    const int r31  = lane & 31;
    const int hl   = lane >> 5;
    const int r7   = r31 & 7;

    // B fragments: x splits for this wave's 32 rows, all of D, in registers.
    bf16x8 xf[3][8];
    {
        const u16* xb = xfrag + (size_t)g * 12288 + lane * 8;
        #pragma unroll
        for (int kk = 0; kk < 8; kk++)
            #pragma unroll
            for (int s = 0; s < 3; s++)
                xf[s][kk] = *(const bf16x8*)(xb + (kk*3 + s) * 512);
    }

    // half-tile range: 43 / 43 / 39 (padding halves >= HREAL skipped)
    int h0, h1;
    if      (blockIdx.y == 0) { h0 = 0;  h1 = 43; }
    else if (blockIdx.y == 1) { h0 = 43; h1 = 86; }
    else                      { h0 = 86; h1 = HREAL; }

    const int soff = w * 3072 + lane * 8;          // this thread's stage slice

    // prologue: stage h0
    {
        const u16* src = psplit_sw + (size_t)h0 * 12288 + soff;
        u16* dst = &buf[h0 & 1][0] + soff;
        #pragma unroll
        for (int j = 0; j < 6; j++) g2lds16(src + j*512, dst + j*512);
    }
    __syncthreads();

    float best = __builtin_inff();
    int bestk = 0;

    for (int h = h0; h < h1; ++h) {
        const int p = h & 1;
        // issue next half's stage first (flies under the MFMAs)
        if (h + 1 < h1) {
            const u16* src = psplit_sw + (size_t)(h + 1) * 12288 + soff;
            u16* dst = &buf[p ^ 1][0] + soff;
            #pragma unroll
            for (int j = 0; j < 6; j++) g2lds16(src + j*512, dst + j*512);
        }

        const u16* B = &buf[p][0];
        f32x16 accA = {0,0,0,0,0,0,0,0,0,0,0,0,0,0,0,0};
        f32x16 accB = {0,0,0,0,0,0,0,0,0,0,0,0,0,0,0,0};
        __builtin_amdgcn_s_setprio(1);
        #pragma unroll
        for (int kk = 0; kk < 8; kk += 2) {
            int c0 = ((kk << 1) | hl) ^ r7;        // swizzled 16B chunk index
            int c1 = (((kk + 1) << 1) | hl) ^ r7;
            const u16* b0 = B + (r31 << 7) + (c0 << 3);
            const u16* b1 = B + (r31 << 7) + (c1 << 3);
            bf16x8 a0h = *(const bf16x8*)(b0);
            bf16x8 a0m = *(const bf16x8*)(b0 + 4096);
            bf16x8 a0l = *(const bf16x8*)(b0 + 8192);
            bf16x8 a1h = *(const bf16x8*)(b1);
            bf16x8 a1m = *(const bf16x8*)(b1 + 4096);
            bf16x8 a1l = *(const bf16x8*)(b1 + 8192);
            bf16x8 b0h = xf[0][kk],   b0m = xf[1][kk],   b0l = xf[2][kk];
            bf16x8 b1h = xf[0][kk+1], b1m = xf[1][kk+1], b1l = xf[2][kk+1];
            // 6 terms down to 2^-18: hh, hm, mh, hl, lh, mm
            accA = mfma16(a0h, b0h, accA);  accB = mfma16(a1h, b1h, accB);
            accA = mfma16(a0h, b0m, accA);  accB = mfma16(a1h, b1m, accB);
            accA = mfma16(a0m, b0h, accA);  accB = mfma16(a1m, b1h, accB);
            accA = mfma16(a0h, b0l, accA);  accB = mfma16(a1h, b1l, accB);
            accA = mfma16(a0l, b0h, accA);  accB = mfma16(a1l, b1h, accB);
            accA = mfma16(a0m, b0m, accA);  accB = mfma16(a1m, b1m, accB);
        }
        __builtin_amdgcn_s_setprio(0);

        // scores + running argmin. C layout: col=lane&31 (x-row),
        // proxy row = (reg&3) + 8*(reg>>2) + 4*hl, reg = 4j+e.
        int kb = h << 5;
        const float* q = p2pad + kb + (hl << 2);
        #pragma unroll
        for (int j = 0; j < 4; j++) {
            float4 qv = *(const float4*)(q + (j << 3));
            float qa[4] = {qv.x, qv.y, qv.z, qv.w};
            #pragma unroll
            for (int e = 0; e < 4; e++) {
                float dot = accA[j*4 + e] + accB[j*4 + e];
                float sc = fmaf(-2.f, dot, qa[e]);
                int ki = kb + (hl << 2) + (j << 3) + e;
                if (sc < best) { best = sc; bestk = ki; }  // strict <: first-min
            }
        }
        asm volatile("s_waitcnt vmcnt(0)" ::: "memory");   // next half staged
        __syncthreads();
    }

    u64 key = ((u64)f2ord(best) << 32) | (unsigned)bestk;
    u64 other = __shfl_xor(key, 32);
    key = other < key ? other : key;
    if (hl == 0) atomicMin(&packed[(size_t)g * 32 + r31], key);
}

// ---------- epilogue copies ----------

// out[N*D : 2*N*D) = proxies[idx]
__global__ void copy_proxy(const float4* __restrict__ prox4,
                           const u64* __restrict__ packed,
                           float4* __restrict__ out4) {
    int i = blockIdx.x * 256 + threadIdx.x;          // 4096 x 256 = N*32
    int n = i >> 5;                                  // DIM/4 = 32
    int d = i & 31;
    int k = (int)(unsigned int)(packed[n] & 0xFFFFFFFFull);
    nt_store4(prox4[(size_t)k * 32 + d], out4 + i);
}

// out[2*N*D : ...) = labels[idx] ; 4 rows/block, 1 wave per row
__global__ void gather_labels(const float4* __restrict__ lab4,
                              const u64* __restrict__ packed,
                              float4* __restrict__ out4) {
    int rr = threadIdx.x >> 6;
    int ln = threadIdx.x & 63;
    int n = blockIdx.x * 4 + rr;                     // 8192 blocks
    int k = (int)(unsigned int)(packed[n] & 0xFFFFFFFFull);
    const float4* src = lab4 + (size_t)k * (CL / 4);
    float4* dst = out4 + (size_t)n * (CL / 4);
    for (int d = ln; d < CL / 4; d += 64)
        nt_store4(src[d], dst + d);
}

extern "C" void kernel_launch(void* const* d_in, const int* in_sizes, int n_in,
                              void* d_out, int out_size, void* d_ws, size_t ws_size,
                              hipStream_t stream) {
    const float* x       = (const float*)d_in[0];
    const float* proxies = (const float*)d_in[1];
    const float* labels  = (const float*)d_in[2];
    float* out = (float*)d_out;

    // workspace map (~28MB):
    //   [0, 256K)        packed u64[32768]
    //   [256K, 272K)     p2pad f32[4096]
    //   [512K, 3.5M)     psplit_sw u16 [128][3][32][128] (pre-swizzled)
    //   [4M, 28M)        xfrag u16 [1024][8][3][64][8]
    u64*   packed    = (u64*)d_ws;
    float* p2pad     = (float*)((char*)d_ws + 262144);
    u16*   psplit_sw = (u16*)((char*)d_ws + 524288);
    u16*   xfrag     = (u16*)((char*)d_ws + 4194304);

    prep_kernel<<<2432, 256, 0, stream>>>(x, proxies, xfrag, psplit_sw,
                                          p2pad, packed, (float4*)out);

    argmin_mfma<<<dim3(256, 3), 256, 0, stream>>>(xfrag, psplit_sw, p2pad, packed);

    copy_proxy<<<4096, 256, 0, stream>>>(
        (const float4*)proxies, packed, (float4*)(out + (size_t)NROWS * DIM));

    gather_labels<<<8192, 256, 0, stream>>>(
        (const float4*)labels, packed, (float4*)(out + 2L * NROWS * DIM));
}